// Round 2
// baseline (582.580 us; speedup 1.0000x reference)
//
#include <hip/hip_runtime.h>

typedef unsigned int uint32;

#define NNODES 32768
#define NGRAPH 128
#define PNODES 256
#define SQ 32
#define NEDGE 524288
#define DIM 128
#define NHEAD 4

// ---------------- degree / dinv ----------------
__global__ void k_init_deg(float* __restrict__ deg){
  deg[blockIdx.x*256 + threadIdx.x] = 1.0f;   // +1 self loop
}

__global__ void k_degree(const int* __restrict__ col, float* __restrict__ deg){
  int e = blockIdx.x*256 + threadIdx.x;       // grid exact: NEDGE/256
  unsafeAtomicAdd(&deg[col[e]], 1.0f);
}

__global__ void k_rsqrt(float* __restrict__ deg){
  int i = blockIdx.x*256 + threadIdx.x;
  deg[i] = rsqrtf(deg[i]);
}

// ---------------- edge scatter: xa[col] += dinv[row]*dinv[col]*x[row] ----------------
// wave per edge; lane handles feature pair (2*lane, 2*lane+1)
__global__ void k_scatter(const int* __restrict__ ei, const float* __restrict__ x,
                          const float* __restrict__ dinv, float* __restrict__ xa){
  const int lane = threadIdx.x & 63;
  const int wid = (blockIdx.x*blockDim.x + threadIdx.x) >> 6;   // grid exact: one wave per edge
  const int r = ei[wid];
  const int c = ei[NEDGE + wid];
  const float coef = dinv[r]*dinv[c];
  const float2 v = *(const float2*)&x[r*128 + 2*lane];
  unsafeAtomicAdd(&xa[c*128 + 2*lane],     coef*v.x);
  unsafeAtomicAdd(&xa[c*128 + 2*lane + 1], coef*v.y);
}

// ---------------- tiled GEMM: out[M,128] = in[M,128] @ W[128,128] + b ----------------
// SELF: effective input = xa + dinv^2 * in (self-loop fused); else plain in (Q path)
// 128x128 tile per block, 256 threads, 8x8 per-thread register tile
template<bool SELF>
__global__ __launch_bounds__(256) void k_gemm(
    const float* __restrict__ in, const float* __restrict__ xa,
    const float* __restrict__ dinv, const float* __restrict__ W,
    const float* __restrict__ b, float* __restrict__ out)
{
  __shared__ __align__(16) float At[128*132];
  __shared__ __align__(16) float Wl[128*132];
  const int t = threadIdx.x;
  const int r0 = blockIdx.x * 128;

  // stage W (f32, float4)
  for (int idx = t; idx < 4096; idx += 256){
    int k = idx >> 5, c4 = idx & 31;
    *(float4*)&Wl[k*132 + c4*4] = *(const float4*)&W[k*128 + c4*4];
  }
  // stage input tile (+ fused self-loop for K/V path)
  for (int idx = t; idx < 4096; idx += 256){
    int r = idx >> 5, c4 = idx & 31;
    float4 v = *(const float4*)&in[(r0+r)*128 + c4*4];
    if (SELF){
      float d = dinv[r0+r];
      float d2 = d*d;
      float4 a = *(const float4*)&xa[(r0+r)*128 + c4*4];
      v.x = a.x + d2*v.x; v.y = a.y + d2*v.y;
      v.z = a.z + d2*v.z; v.w = a.w + d2*v.w;
    }
    *(float4*)&At[r*132 + c4*4] = v;
  }
  __syncthreads();

  const int lane = t & 63, w = t >> 6;
  const int cg = lane & 15;                // column group: cols cg*4 + {0..3} (+64)
  const int rg = (lane >> 4) + (w << 2);   // 0..15; rows rg + 16*i

  float acc[8][8];
  #pragma unroll
  for (int jj = 0; jj < 2; ++jj){
    const float4 bv = *(const float4*)&b[jj*64 + cg*4];
    #pragma unroll
    for (int i = 0; i < 8; ++i){
      acc[i][jj*4+0] = bv.x; acc[i][jj*4+1] = bv.y;
      acc[i][jj*4+2] = bv.z; acc[i][jj*4+3] = bv.w;
    }
  }

  #pragma unroll 1
  for (int kk = 0; kk < 32; ++kk){
    float4 a[8];
    #pragma unroll
    for (int i = 0; i < 8; ++i)
      a[i] = *(const float4*)&At[(rg + 16*i)*132 + kk*4];
    #pragma unroll
    for (int u = 0; u < 4; ++u){
      const float4 w0 = *(const float4*)&Wl[(kk*4+u)*132 + cg*4];
      const float4 w1 = *(const float4*)&Wl[(kk*4+u)*132 + 64 + cg*4];
      #pragma unroll
      for (int i = 0; i < 8; ++i){
        float av = (u==0) ? a[i].x : (u==1) ? a[i].y : (u==2) ? a[i].z : a[i].w;
        acc[i][0] = fmaf(av, w0.x, acc[i][0]);
        acc[i][1] = fmaf(av, w0.y, acc[i][1]);
        acc[i][2] = fmaf(av, w0.z, acc[i][2]);
        acc[i][3] = fmaf(av, w0.w, acc[i][3]);
        acc[i][4] = fmaf(av, w1.x, acc[i][4]);
        acc[i][5] = fmaf(av, w1.y, acc[i][5]);
        acc[i][6] = fmaf(av, w1.z, acc[i][6]);
        acc[i][7] = fmaf(av, w1.w, acc[i][7]);
      }
    }
  }

  #pragma unroll
  for (int i = 0; i < 8; ++i){
    int r = r0 + rg + 16*i;
    #pragma unroll
    for (int jj = 0; jj < 2; ++jj){
      float4 o;
      o.x = acc[i][jj*4+0]; o.y = acc[i][jj*4+1];
      o.z = acc[i][jj*4+2]; o.w = acc[i][jj*4+3];
      *(float4*)&out[r*128 + jj*64 + cg*4] = o;
    }
  }
}

// ---------------- attention per (graph, head) ----------------
__global__ __launch_bounds__(256) void k_attn(
    const float* __restrict__ Qp, const float* __restrict__ K,
    const float* __restrict__ V, float* __restrict__ Oat)
{
  __shared__ __align__(16) float Pr[32*260];   // scores / A
  __shared__ __align__(16) float Vs[256*36];   // V rows (head slice), padded
  const int t = threadIdx.x;                    // = key index p
  const int b = blockIdx.x >> 2, h = blockIdx.x & 3;

  float kreg[32];
  {
    const float* kp = K + (b*256 + t)*128 + h*32;
    #pragma unroll
    for (int q = 0; q < 8; ++q){
      const float4 v = *(const float4*)&kp[q*4];
      kreg[4*q]   = v.x; kreg[4*q+1] = v.y;
      kreg[4*q+2] = v.z; kreg[4*q+3] = v.w;
    }
    const float* vp = V + (b*256 + t)*128 + h*32;
    #pragma unroll
    for (int q = 0; q < 8; ++q)
      *(float4*)&Vs[t*36 + q*4] = *(const float4*)&vp[q*4];
  }
  // scores: thread t owns key p=t; Q reads are wave-uniform (scalar-load friendly)
  const float* qb = Qp + (b*32)*128 + h*32;
  #pragma unroll 1
  for (int s = 0; s < 32; ++s){
    float acc = 0.f;
    #pragma unroll
    for (int d = 0; d < 32; ++d)
      acc = fmaf(qb[s*128 + d], kreg[d], acc);
    Pr[s*260 + t] = acc * 0.08838834764831845f;   // 1/sqrt(128)
  }
  __syncthreads();
  // softmax over p: 8 threads per query row
  {
    const int ss = t >> 3, pg = t & 7;
    float vals[32];
    float m = -1e30f;
    #pragma unroll
    for (int u = 0; u < 32; ++u){
      vals[u] = Pr[ss*260 + pg + 8*u];
      m = fmaxf(m, vals[u]);
    }
    m = fmaxf(m, __shfl_xor(m, 1));
    m = fmaxf(m, __shfl_xor(m, 2));
    m = fmaxf(m, __shfl_xor(m, 4));
    float sum = 0.f;
    #pragma unroll
    for (int u = 0; u < 32; ++u){
      vals[u] = __expf(vals[u] - m);
      sum += vals[u];
    }
    sum += __shfl_xor(sum, 1);
    sum += __shfl_xor(sum, 2);
    sum += __shfl_xor(sum, 4);
    float inv = 1.f / sum;
    #pragma unroll
    for (int u = 0; u < 32; ++u)
      Pr[ss*260 + pg + 8*u] = vals[u] * inv;
  }
  __syncthreads();
  // PV + residual Q
  {
    const int ss = t >> 3, dg = t & 7;
    float o0=0.f,o1=0.f,o2=0.f,o3=0.f;
    #pragma unroll 4
    for (int p = 0; p < 256; ++p){
      float a = Pr[ss*260 + p];
      const float4 v = *(const float4*)&Vs[p*36 + dg*4];
      o0 = fmaf(a, v.x, o0); o1 = fmaf(a, v.y, o1);
      o2 = fmaf(a, v.z, o2); o3 = fmaf(a, v.w, o3);
    }
    const int off = (b*32 + ss)*128 + h*32 + dg*4;
    const float4 q = *(const float4*)(Qp + off);
    float4 o; o.x = o0+q.x; o.y = o1+q.y; o.z = o2+q.z; o.w = o3+q.w;
    *(float4*)(Oat + off) = o;
  }
}

// ---------------- epilogue: LN0 -> +relu(.@Wo+bo) -> LN1 -> f32 out ----------------
__global__ __launch_bounds__(256) void k_epi(
    const float* __restrict__ Oat, const float* __restrict__ Wo,
    const float* __restrict__ bo, const float* __restrict__ g0,
    const float* __restrict__ b0, const float* __restrict__ g1,
    const float* __restrict__ b1, float* __restrict__ out)
{
  __shared__ float rb[4][132];
  const int w = threadIdx.x >> 6, lane = threadIdx.x & 63;
  const int row = blockIdx.x*4 + w;
  const float2 xv = *(const float2*)(Oat + row*128 + 2*lane);
  float x0 = xv.x, x1 = xv.y;
  float s = x0 + x1;
  s += __shfl_xor(s,1); s += __shfl_xor(s,2); s += __shfl_xor(s,4);
  s += __shfl_xor(s,8); s += __shfl_xor(s,16); s += __shfl_xor(s,32);
  float mu = s * 0.0078125f;
  float d0 = x0 - mu, d1 = x1 - mu;
  float vv = d0*d0 + d1*d1;
  vv += __shfl_xor(vv,1); vv += __shfl_xor(vv,2); vv += __shfl_xor(vv,4);
  vv += __shfl_xor(vv,8); vv += __shfl_xor(vv,16); vv += __shfl_xor(vv,32);
  float rs = rsqrtf(vv*0.0078125f + 1e-5f);
  const float2 gv = *(const float2*)&g0[2*lane];
  const float2 bv = *(const float2*)&b0[2*lane];
  float y0 = d0*rs*gv.x + bv.x;
  float y1 = d1*rs*gv.y + bv.y;
  rb[w][2*lane] = y0; rb[w][2*lane+1] = y1;
  __syncthreads();
  const float2 bov = *(const float2*)&bo[2*lane];
  float a0 = bov.x, a1 = bov.y;
  #pragma unroll 4
  for (int k = 0; k < 128; ++k){
    float yk = rb[w][k];
    const float2 wv = *(const float2*)&Wo[k*128 + 2*lane];
    a0 = fmaf(yk, wv.x, a0);
    a1 = fmaf(yk, wv.y, a1);
  }
  float z0 = y0 + fmaxf(a0, 0.f);
  float z1 = y1 + fmaxf(a1, 0.f);
  s = z0 + z1;
  s += __shfl_xor(s,1); s += __shfl_xor(s,2); s += __shfl_xor(s,4);
  s += __shfl_xor(s,8); s += __shfl_xor(s,16); s += __shfl_xor(s,32);
  mu = s * 0.0078125f;
  d0 = z0 - mu; d1 = z1 - mu;
  vv = d0*d0 + d1*d1;
  vv += __shfl_xor(vv,1); vv += __shfl_xor(vv,2); vv += __shfl_xor(vv,4);
  vv += __shfl_xor(vv,8); vv += __shfl_xor(vv,16); vv += __shfl_xor(vv,32);
  rs = rsqrtf(vv*0.0078125f + 1e-5f);
  const float2 g1v = *(const float2*)&g1[2*lane];
  const float2 b1v = *(const float2*)&b1[2*lane];
  float o0 = d0*rs*g1v.x + b1v.x;
  float o1 = d1*rs*g1v.y + b1v.y;
  float2 o; o.x = o0; o.y = o1;
  *(float2*)&out[row*128 + 2*lane] = o;
}

extern "C" void kernel_launch(void* const* d_in, const int* in_sizes, int n_in,
                              void* d_out, int out_size, void* d_ws, size_t ws_size,
                              hipStream_t stream){
  const float* Q   = (const float*)d_in[0];
  const float* x   = (const float*)d_in[1];
  const int*   ei  = (const int*)d_in[2];
  // d_in[3] = batch (unused; graphs are equal-size contiguous blocks)
  const float* Wq  = (const float*)d_in[4];
  const float* bq  = (const float*)d_in[5];
  const float* Wk  = (const float*)d_in[6];
  const float* bk  = (const float*)d_in[7];
  const float* Wv  = (const float*)d_in[8];
  const float* bv  = (const float*)d_in[9];
  const float* Wo  = (const float*)d_in[10];
  const float* bo  = (const float*)d_in[11];
  const float* g0  = (const float*)d_in[12];
  const float* b0  = (const float*)d_in[13];
  const float* g1  = (const float*)d_in[14];
  const float* b1  = (const float*)d_in[15];

  char* ws = (char*)d_ws;
  float* xa   = (float*)(ws);                    // 16 MB  [N,128] aggregated x
  float* dinv = (float*)(ws + 16777216);         // 128 KB (deg -> dinv in place)
  float* Kf   = (float*)(ws + 16908288);         // 16 MB
  float* Vf   = (float*)(ws + 33685504);         // 16 MB
  float* Qp   = (float*)(ws + 50462720);         // 2 MB
  float* Oat  = (float*)(ws + 52559872);         // 2 MB   (total ~52.1 MB)

  hipMemsetAsync(xa, 0, (size_t)NNODES*128*4, stream);
  k_init_deg<<<NNODES/256, 256, 0, stream>>>(dinv);
  k_degree<<<NEDGE/256, 256, 0, stream>>>(ei + NEDGE, dinv);
  k_rsqrt<<<NNODES/256, 256, 0, stream>>>(dinv);
  k_scatter<<<NEDGE/4, 256, 0, stream>>>(ei, x, dinv, xa);   // one wave per edge
  k_gemm<false><<<(NGRAPH*SQ)/128, 256, 0, stream>>>(Q, nullptr, nullptr, Wq, bq, Qp);
  k_gemm<true ><<<NNODES/128, 256, 0, stream>>>(x, xa, dinv, Wk, bk, Kf);
  k_gemm<true ><<<NNODES/128, 256, 0, stream>>>(x, xa, dinv, Wv, bv, Vf);
  k_attn<<<NGRAPH*NHEAD, 256, 0, stream>>>(Qp, Kf, Vf, Oat);
  k_epi<<<(NGRAPH*SQ)/4, 256, 0, stream>>>(Oat, Wo, bo, g0, b0, g1, b1, (float*)d_out);
}

// Round 3
// 209.564 us; speedup vs baseline: 2.7800x; 2.7800x over previous
//
#include <hip/hip_runtime.h>

typedef unsigned int uint32;

#define NNODES 32768
#define NGRAPH 128
#define PNODES 256
#define SQ 32
#define NEDGE 524288
#define DIM 128
#define NHEAD 4

// ---------------- histogram of dst (in-degree, excl. self-loop) ----------------
__global__ void k_hist(const int* __restrict__ dst, int* __restrict__ cnt){
  int e = blockIdx.x*256 + threadIdx.x;        // grid exact: NEDGE/256
  atomicAdd(&cnt[dst[e]], 1);
}

// ---------------- exclusive prefix sum over 32768 counts (single block) ----------------
__global__ __launch_bounds__(1024) void k_scan(const int* __restrict__ cnt,
                                               int* __restrict__ start,
                                               int* __restrict__ wptr){
  __shared__ int ps[1024];
  const int t = threadIdx.x;
  const int base = t*32;
  int loc[32];
  int s = 0;
  #pragma unroll
  for (int i = 0; i < 32; ++i){ loc[i] = s; s += cnt[base+i]; }
  ps[t] = s;
  __syncthreads();
  #pragma unroll 1
  for (int off = 1; off < 1024; off <<= 1){
    int v = (t >= off) ? ps[t-off] : 0;
    __syncthreads();
    ps[t] += v;
    __syncthreads();
  }
  const int pre = (t == 0) ? 0 : ps[t-1];
  #pragma unroll
  for (int i = 0; i < 32; ++i){
    int v = pre + loc[i];
    start[base+i] = v;
    wptr[base+i]  = v;
  }
  if (t == 0) start[NNODES] = NEDGE;
}

// ---------------- dinv = rsqrt(deg), deg = in-degree + 1 ----------------
__global__ void k_rsqrt(const int* __restrict__ cnt, float* __restrict__ dinv){
  int i = blockIdx.x*256 + threadIdx.x;
  dinv[i] = rsqrtf((float)(cnt[i] + 1));
}

// ---------------- bucket edges by dst (counting-sort scatter) ----------------
__global__ void k_sort(const int* __restrict__ ei, int* __restrict__ wptr,
                       int* __restrict__ ssrc){
  int e = blockIdx.x*256 + threadIdx.x;        // grid exact: NEDGE/256
  int s = ei[e];
  int d = ei[NEDGE + e];
  int pos = atomicAdd(&wptr[d], 1);
  ssrc[pos] = s;
}

// ---------------- gather: xa[n] = sum_in coef*x[src] + dinv^2*x[n] ----------------
// one wave per node; lane owns feature pair (2*lane, 2*lane+1); no atomics
__global__ __launch_bounds__(256) void k_gather(const int* __restrict__ start,
    const int* __restrict__ ssrc, const float* __restrict__ x,
    const float* __restrict__ dinv, float* __restrict__ xa){
  const int lane = threadIdx.x & 63;
  const int n = __builtin_amdgcn_readfirstlane((blockIdx.x*256 + threadIdx.x) >> 6);
  const int s0 = start[n], s1 = start[n+1];
  const float dn = dinv[n];
  const float2 xv = *(const float2*)&x[n*128 + 2*lane];
  float a0 = dn*dn*xv.x, a1 = dn*dn*xv.y;
  int e = s0;
  for (; e + 2 <= s1; e += 2){
    int sA = ssrc[e], sB = ssrc[e+1];
    float cA = dn*dinv[sA], cB = dn*dinv[sB];
    const float2 vA = *(const float2*)&x[sA*128 + 2*lane];
    const float2 vB = *(const float2*)&x[sB*128 + 2*lane];
    a0 = fmaf(cA, vA.x, a0); a1 = fmaf(cA, vA.y, a1);
    a0 = fmaf(cB, vB.x, a0); a1 = fmaf(cB, vB.y, a1);
  }
  if (e < s1){
    int sA = ssrc[e];
    float cA = dn*dinv[sA];
    const float2 vA = *(const float2*)&x[sA*128 + 2*lane];
    a0 = fmaf(cA, vA.x, a0); a1 = fmaf(cA, vA.y, a1);
  }
  float2 o; o.x = a0; o.y = a1;
  *(float2*)&xa[n*128 + 2*lane] = o;
}

// ---------------- tiled GEMM: out[M,128] = in[M,128] @ W[128,128] + b ----------------
// 128x128 tile per block, 256 threads, 8x8 per-thread register tile
__global__ __launch_bounds__(256) void k_gemm(
    const float* __restrict__ in, const float* __restrict__ W,
    const float* __restrict__ b, float* __restrict__ out)
{
  __shared__ __align__(16) float At[128*132];
  __shared__ __align__(16) float Wl[128*132];
  const int t = threadIdx.x;
  const int r0 = blockIdx.x * 128;

  for (int idx = t; idx < 4096; idx += 256){
    int k = idx >> 5, c4 = idx & 31;
    *(float4*)&Wl[k*132 + c4*4] = *(const float4*)&W[k*128 + c4*4];
  }
  for (int idx = t; idx < 4096; idx += 256){
    int r = idx >> 5, c4 = idx & 31;
    *(float4*)&At[r*132 + c4*4] = *(const float4*)&in[(r0+r)*128 + c4*4];
  }
  __syncthreads();

  const int lane = t & 63, w = t >> 6;
  const int cg = lane & 15;                // column group: cols cg*4 + {0..3} (+64)
  const int rg = (lane >> 4) + (w << 2);   // 0..15; rows rg + 16*i

  float acc[8][8];
  #pragma unroll
  for (int jj = 0; jj < 2; ++jj){
    const float4 bv = *(const float4*)&b[jj*64 + cg*4];
    #pragma unroll
    for (int i = 0; i < 8; ++i){
      acc[i][jj*4+0] = bv.x; acc[i][jj*4+1] = bv.y;
      acc[i][jj*4+2] = bv.z; acc[i][jj*4+3] = bv.w;
    }
  }

  #pragma unroll 1
  for (int kk = 0; kk < 32; ++kk){
    float4 a[8];
    #pragma unroll
    for (int i = 0; i < 8; ++i)
      a[i] = *(const float4*)&At[(rg + 16*i)*132 + kk*4];
    #pragma unroll
    for (int u = 0; u < 4; ++u){
      const float4 w0 = *(const float4*)&Wl[(kk*4+u)*132 + cg*4];
      const float4 w1 = *(const float4*)&Wl[(kk*4+u)*132 + 64 + cg*4];
      #pragma unroll
      for (int i = 0; i < 8; ++i){
        float av = (u==0) ? a[i].x : (u==1) ? a[i].y : (u==2) ? a[i].z : a[i].w;
        acc[i][0] = fmaf(av, w0.x, acc[i][0]);
        acc[i][1] = fmaf(av, w0.y, acc[i][1]);
        acc[i][2] = fmaf(av, w0.z, acc[i][2]);
        acc[i][3] = fmaf(av, w0.w, acc[i][3]);
        acc[i][4] = fmaf(av, w1.x, acc[i][4]);
        acc[i][5] = fmaf(av, w1.y, acc[i][5]);
        acc[i][6] = fmaf(av, w1.z, acc[i][6]);
        acc[i][7] = fmaf(av, w1.w, acc[i][7]);
      }
    }
  }

  #pragma unroll
  for (int i = 0; i < 8; ++i){
    int r = r0 + rg + 16*i;
    #pragma unroll
    for (int jj = 0; jj < 2; ++jj){
      float4 o;
      o.x = acc[i][jj*4+0]; o.y = acc[i][jj*4+1];
      o.z = acc[i][jj*4+2]; o.w = acc[i][jj*4+3];
      *(float4*)&out[r*128 + jj*64 + cg*4] = o;
    }
  }
}

// ---------------- attention per (graph, head) ----------------
__global__ __launch_bounds__(256) void k_attn(
    const float* __restrict__ Qp, const float* __restrict__ K,
    const float* __restrict__ V, float* __restrict__ Oat)
{
  __shared__ __align__(16) float Pr[32*260];   // scores / A
  __shared__ __align__(16) float Vs[256*36];   // V rows (head slice), padded
  const int t = threadIdx.x;                    // = key index p
  const int b = blockIdx.x >> 2, h = blockIdx.x & 3;

  float kreg[32];
  {
    const float* kp = K + (b*256 + t)*128 + h*32;
    #pragma unroll
    for (int q = 0; q < 8; ++q){
      const float4 v = *(const float4*)&kp[q*4];
      kreg[4*q]   = v.x; kreg[4*q+1] = v.y;
      kreg[4*q+2] = v.z; kreg[4*q+3] = v.w;
    }
    const float* vp = V + (b*256 + t)*128 + h*32;
    #pragma unroll
    for (int q = 0; q < 8; ++q)
      *(float4*)&Vs[t*36 + q*4] = *(const float4*)&vp[q*4];
  }
  const float* qb = Qp + (b*32)*128 + h*32;
  #pragma unroll 1
  for (int s = 0; s < 32; ++s){
    float acc = 0.f;
    #pragma unroll
    for (int d = 0; d < 32; ++d)
      acc = fmaf(qb[s*128 + d], kreg[d], acc);
    Pr[s*260 + t] = acc * 0.08838834764831845f;   // 1/sqrt(128)
  }
  __syncthreads();
  // softmax over p: 8 threads per query row
  {
    const int ss = t >> 3, pg = t & 7;
    float vals[32];
    float m = -1e30f;
    #pragma unroll
    for (int u = 0; u < 32; ++u){
      vals[u] = Pr[ss*260 + pg + 8*u];
      m = fmaxf(m, vals[u]);
    }
    m = fmaxf(m, __shfl_xor(m, 1));
    m = fmaxf(m, __shfl_xor(m, 2));
    m = fmaxf(m, __shfl_xor(m, 4));
    float sum = 0.f;
    #pragma unroll
    for (int u = 0; u < 32; ++u){
      vals[u] = __expf(vals[u] - m);
      sum += vals[u];
    }
    sum += __shfl_xor(sum, 1);
    sum += __shfl_xor(sum, 2);
    sum += __shfl_xor(sum, 4);
    float inv = 1.f / sum;
    #pragma unroll
    for (int u = 0; u < 32; ++u)
      Pr[ss*260 + pg + 8*u] = vals[u] * inv;
  }
  __syncthreads();
  // PV + residual Q
  {
    const int ss = t >> 3, dg = t & 7;
    float o0=0.f,o1=0.f,o2=0.f,o3=0.f;
    #pragma unroll 4
    for (int p = 0; p < 256; ++p){
      float a = Pr[ss*260 + p];
      const float4 v = *(const float4*)&Vs[p*36 + dg*4];
      o0 = fmaf(a, v.x, o0); o1 = fmaf(a, v.y, o1);
      o2 = fmaf(a, v.z, o2); o3 = fmaf(a, v.w, o3);
    }
    const int off = (b*32 + ss)*128 + h*32 + dg*4;
    const float4 q = *(const float4*)(Qp + off);
    float4 o; o.x = o0+q.x; o.y = o1+q.y; o.z = o2+q.z; o.w = o3+q.w;
    *(float4*)(Oat + off) = o;
  }
}

// ---------------- epilogue: LN0 -> +relu(.@Wo+bo) -> LN1 -> f32 out ----------------
__global__ __launch_bounds__(256) void k_epi(
    const float* __restrict__ Oat, const float* __restrict__ Wo,
    const float* __restrict__ bo, const float* __restrict__ g0,
    const float* __restrict__ b0, const float* __restrict__ g1,
    const float* __restrict__ b1, float* __restrict__ out)
{
  __shared__ float rb[4][132];
  const int w = threadIdx.x >> 6, lane = threadIdx.x & 63;
  const int row = blockIdx.x*4 + w;
  const float2 xv = *(const float2*)(Oat + row*128 + 2*lane);
  float x0 = xv.x, x1 = xv.y;
  float s = x0 + x1;
  s += __shfl_xor(s,1); s += __shfl_xor(s,2); s += __shfl_xor(s,4);
  s += __shfl_xor(s,8); s += __shfl_xor(s,16); s += __shfl_xor(s,32);
  float mu = s * 0.0078125f;
  float d0 = x0 - mu, d1 = x1 - mu;
  float vv = d0*d0 + d1*d1;
  vv += __shfl_xor(vv,1); vv += __shfl_xor(vv,2); vv += __shfl_xor(vv,4);
  vv += __shfl_xor(vv,8); vv += __shfl_xor(vv,16); vv += __shfl_xor(vv,32);
  float rs = rsqrtf(vv*0.0078125f + 1e-5f);
  const float2 gv = *(const float2*)&g0[2*lane];
  const float2 bv = *(const float2*)&b0[2*lane];
  float y0 = d0*rs*gv.x + bv.x;
  float y1 = d1*rs*gv.y + bv.y;
  rb[w][2*lane] = y0; rb[w][2*lane+1] = y1;
  __syncthreads();
  const float2 bov = *(const float2*)&bo[2*lane];
  float a0 = bov.x, a1 = bov.y;
  #pragma unroll 4
  for (int k = 0; k < 128; ++k){
    float yk = rb[w][k];
    const float2 wv = *(const float2*)&Wo[k*128 + 2*lane];
    a0 = fmaf(yk, wv.x, a0);
    a1 = fmaf(yk, wv.y, a1);
  }
  float z0 = y0 + fmaxf(a0, 0.f);
  float z1 = y1 + fmaxf(a1, 0.f);
  s = z0 + z1;
  s += __shfl_xor(s,1); s += __shfl_xor(s,2); s += __shfl_xor(s,4);
  s += __shfl_xor(s,8); s += __shfl_xor(s,16); s += __shfl_xor(s,32);
  mu = s * 0.0078125f;
  d0 = z0 - mu; d1 = z1 - mu;
  vv = d0*d0 + d1*d1;
  vv += __shfl_xor(vv,1); vv += __shfl_xor(vv,2); vv += __shfl_xor(vv,4);
  vv += __shfl_xor(vv,8); vv += __shfl_xor(vv,16); vv += __shfl_xor(vv,32);
  rs = rsqrtf(vv*0.0078125f + 1e-5f);
  const float2 g1v = *(const float2*)&g1[2*lane];
  const float2 b1v = *(const float2*)&b1[2*lane];
  float o0 = d0*rs*g1v.x + b1v.x;
  float o1 = d1*rs*g1v.y + b1v.y;
  float2 o; o.x = o0; o.y = o1;
  *(float2*)&out[row*128 + 2*lane] = o;
}

extern "C" void kernel_launch(void* const* d_in, const int* in_sizes, int n_in,
                              void* d_out, int out_size, void* d_ws, size_t ws_size,
                              hipStream_t stream){
  const float* Q   = (const float*)d_in[0];
  const float* x   = (const float*)d_in[1];
  const int*   ei  = (const int*)d_in[2];
  // d_in[3] = batch (unused; graphs are equal-size contiguous blocks)
  const float* Wq  = (const float*)d_in[4];
  const float* bq  = (const float*)d_in[5];
  const float* Wk  = (const float*)d_in[6];
  const float* bk  = (const float*)d_in[7];
  const float* Wv  = (const float*)d_in[8];
  const float* bv  = (const float*)d_in[9];
  const float* Wo  = (const float*)d_in[10];
  const float* bo  = (const float*)d_in[11];
  const float* g0  = (const float*)d_in[12];
  const float* b0  = (const float*)d_in[13];
  const float* g1  = (const float*)d_in[14];
  const float* b1  = (const float*)d_in[15];

  // workspace layout (time-aliased; total 54,657,024 B == round-1 footprint)
  char* ws = (char*)d_ws;
  float* xa   = (float*)(ws);                    // [0,16M)   aggregated features
  float* Kf   = (float*)(ws + 16777216);         // [16M,32M)
  float* Vf   = (float*)(ws + 33554432);         // [32M,48M)
  float* Qp   = (float*)(ws + 50331648);         // [48M,50M)
  float* Oat  = (float*)(ws + 52428800);         // [50M,52M)
  float* dinv = (float*)(ws + 54525952);         // [52M, +128K)
  int*   cnt  = (int*)(ws + 16777216);           // aliases Kf   (dead before gemm-K)
  int*   start= (int*)(ws + 33554432);           // aliases Vf   (dead before gemm-V)
  int*   wptr = (int*)(ws + 50331648);           // aliases Qp   (dead before gemm-Q)
  int*   ssrc = (int*)(ws + 52428800);           // aliases Oat  (dead before attn)

  hipMemsetAsync(cnt, 0, NNODES*4, stream);
  k_hist<<<NEDGE/256, 256, 0, stream>>>(ei + NEDGE, cnt);
  k_scan<<<1, 1024, 0, stream>>>(cnt, start, wptr);
  k_rsqrt<<<NNODES/256, 256, 0, stream>>>(cnt, dinv);
  k_sort<<<NEDGE/256, 256, 0, stream>>>(ei, wptr, ssrc);
  k_gather<<<NNODES/4, 256, 0, stream>>>(start, ssrc, x, dinv, xa);
  k_gemm<<<(NGRAPH*SQ)/128, 256, 0, stream>>>(Q, Wq, bq, Qp);
  k_gemm<<<NNODES/128, 256, 0, stream>>>(xa, Wk, bk, Kf);
  k_gemm<<<NNODES/128, 256, 0, stream>>>(xa, Wv, bv, Vf);
  k_attn<<<NGRAPH*NHEAD, 256, 0, stream>>>(Qp, Kf, Vf, Oat);
  k_epi<<<(NGRAPH*SQ)/4, 256, 0, stream>>>(Oat, Wo, bo, g0, b0, g1, b1, (float*)d_out);
}

// Round 4
// 207.155 us; speedup vs baseline: 2.8123x; 1.0116x over previous
//
#include <hip/hip_runtime.h>

typedef unsigned int uint32;

#define NNODES 32768
#define NGRAPH 128
#define PNODES 256
#define SQ 32
#define NEDGE 524288
#define DIM 128
#define NHEAD 4

// ---------------- zero the histogram (replaces rocclr fill) ----------------
__global__ void k_zero(int4* __restrict__ p){
  p[blockIdx.x*256 + threadIdx.x] = int4{0,0,0,0};   // grid exact: 32768*4B/16B/256
}

// ---------------- histogram of dst (in-degree, excl. self-loop) ----------------
__global__ void k_hist(const int* __restrict__ dst, int* __restrict__ cnt){
  int e = blockIdx.x*256 + threadIdx.x;        // grid exact: NEDGE/256
  atomicAdd(&cnt[dst[e]], 1);
}

// ---------------- exclusive prefix sum over 32768 counts + dinv ----------------
__global__ __launch_bounds__(1024) void k_scan(const int* __restrict__ cnt,
                                               int* __restrict__ start,
                                               int* __restrict__ wptr,
                                               float* __restrict__ dinv){
  __shared__ int ps[1024];
  const int t = threadIdx.x;
  const int base = t*32;
  int loc[32];
  int s = 0;
  #pragma unroll
  for (int i = 0; i < 32; ++i){
    int c = cnt[base+i];
    loc[i] = s; s += c;
    dinv[base+i] = rsqrtf((float)(c + 1));
  }
  ps[t] = s;
  __syncthreads();
  #pragma unroll 1
  for (int off = 1; off < 1024; off <<= 1){
    int v = (t >= off) ? ps[t-off] : 0;
    __syncthreads();
    ps[t] += v;
    __syncthreads();
  }
  const int pre = (t == 0) ? 0 : ps[t-1];
  #pragma unroll
  for (int i = 0; i < 32; ++i){
    int v = pre + loc[i];
    start[base+i] = v;
    wptr[base+i]  = v;
  }
  if (t == 0) start[NNODES] = NEDGE;
}

// ---------------- bucket edges by dst (counting-sort scatter) ----------------
__global__ void k_sort(const int* __restrict__ ei, int* __restrict__ wptr,
                       int* __restrict__ ssrc){
  int e = blockIdx.x*256 + threadIdx.x;        // grid exact: NEDGE/256
  int s = ei[e];
  int d = ei[NEDGE + e];
  int pos = atomicAdd(&wptr[d], 1);
  ssrc[pos] = s;
}

// ---------------- gather with per-graph LDS staging ----------------
// 2 blocks per graph; block stages the graph's full x-slice (256x128 f32 = 128KB)
// + dinv slice, then each wave gathers 16 nodes entirely from LDS. No atomics.
__global__ __launch_bounds__(512) void k_gather(const int* __restrict__ start,
    const int* __restrict__ ssrc, const float* __restrict__ x,
    const float* __restrict__ dinv, float* __restrict__ xa){
  __shared__ __align__(16) float xs[PNODES*DIM];   // 128 KB
  __shared__ float dvs[PNODES];                    // 1 KB
  const int g = blockIdx.x >> 1;                   // graph id
  const int half = blockIdx.x & 1;                 // which 128 nodes
  const int t = threadIdx.x;
  const int base = g*PNODES;

  {
    const float4* xg = (const float4*)&x[base*DIM];
    float4* xs4 = (float4*)xs;
    #pragma unroll
    for (int i = 0; i < 16; ++i)
      xs4[t + i*512] = xg[t + i*512];
    if (t < PNODES) dvs[t] = dinv[base + t];
  }
  __syncthreads();

  const int wave = t >> 6, lane = t & 63;
  #pragma unroll 1
  for (int ni = 0; ni < 16; ++ni){
    const int nl = __builtin_amdgcn_readfirstlane(half*128 + wave*16 + ni);
    const int n  = base + nl;
    const int s0 = start[n], s1 = start[n+1];
    const float dn = dvs[nl];
    const float2 xv = *(const float2*)&xs[nl*DIM + 2*lane];
    float a0 = dn*dn*xv.x, a1 = dn*dn*xv.y;
    int e = s0;
    for (; e + 2 <= s1; e += 2){
      int slA = ssrc[e]   - base;
      int slB = ssrc[e+1] - base;
      float cA = dn*dvs[slA], cB = dn*dvs[slB];
      const float2 vA = *(const float2*)&xs[slA*DIM + 2*lane];
      const float2 vB = *(const float2*)&xs[slB*DIM + 2*lane];
      a0 = fmaf(cA, vA.x, a0); a1 = fmaf(cA, vA.y, a1);
      a0 = fmaf(cB, vB.x, a0); a1 = fmaf(cB, vB.y, a1);
    }
    if (e < s1){
      int slA = ssrc[e] - base;
      float cA = dn*dvs[slA];
      const float2 vA = *(const float2*)&xs[slA*DIM + 2*lane];
      a0 = fmaf(cA, vA.x, a0); a1 = fmaf(cA, vA.y, a1);
    }
    float2 o; o.x = a0; o.y = a1;
    *(float2*)&xa[n*DIM + 2*lane] = o;
  }
}

// ---------------- fused GEMM: K (blk 0-255), V (256-511), Q (512-543) ----------------
// out[M,128] = in[M,128] @ W[128,128] + b ; 128x128 tile, 8x8 register tile
__global__ __launch_bounds__(256) void k_gemm3(
    const float* __restrict__ xa, const float* __restrict__ Qin,
    const float* __restrict__ Wk, const float* __restrict__ bk, float* __restrict__ Kf,
    const float* __restrict__ Wv, const float* __restrict__ bv, float* __restrict__ Vf,
    const float* __restrict__ Wq, const float* __restrict__ bq, float* __restrict__ Qp)
{
  __shared__ __align__(16) float At[128*132];
  __shared__ __align__(16) float Wl[128*132];
  const int bid = blockIdx.x;
  const float *in, *W, *bias; float* out; int r0;
  if (bid < 256){ in = xa;  W = Wk; bias = bk; out = Kf; r0 = bid*128; }
  else if (bid < 512){ in = xa;  W = Wv; bias = bv; out = Vf; r0 = (bid-256)*128; }
  else { in = Qin; W = Wq; bias = bq; out = Qp; r0 = (bid-512)*128; }

  const int t = threadIdx.x;
  for (int idx = t; idx < 4096; idx += 256){
    int k = idx >> 5, c4 = idx & 31;
    *(float4*)&Wl[k*132 + c4*4] = *(const float4*)&W[k*128 + c4*4];
  }
  for (int idx = t; idx < 4096; idx += 256){
    int r = idx >> 5, c4 = idx & 31;
    *(float4*)&At[r*132 + c4*4] = *(const float4*)&in[(r0+r)*128 + c4*4];
  }
  __syncthreads();

  const int lane = t & 63, w = t >> 6;
  const int cg = lane & 15;
  const int rg = (lane >> 4) + (w << 2);

  float acc[8][8];
  #pragma unroll
  for (int jj = 0; jj < 2; ++jj){
    const float4 bv4 = *(const float4*)&bias[jj*64 + cg*4];
    #pragma unroll
    for (int i = 0; i < 8; ++i){
      acc[i][jj*4+0] = bv4.x; acc[i][jj*4+1] = bv4.y;
      acc[i][jj*4+2] = bv4.z; acc[i][jj*4+3] = bv4.w;
    }
  }

  #pragma unroll 1
  for (int kk = 0; kk < 32; ++kk){
    float4 a[8];
    #pragma unroll
    for (int i = 0; i < 8; ++i)
      a[i] = *(const float4*)&At[(rg + 16*i)*132 + kk*4];
    #pragma unroll
    for (int u = 0; u < 4; ++u){
      const float4 w0 = *(const float4*)&Wl[(kk*4+u)*132 + cg*4];
      const float4 w1 = *(const float4*)&Wl[(kk*4+u)*132 + 64 + cg*4];
      #pragma unroll
      for (int i = 0; i < 8; ++i){
        float av = (u==0) ? a[i].x : (u==1) ? a[i].y : (u==2) ? a[i].z : a[i].w;
        acc[i][0] = fmaf(av, w0.x, acc[i][0]);
        acc[i][1] = fmaf(av, w0.y, acc[i][1]);
        acc[i][2] = fmaf(av, w0.z, acc[i][2]);
        acc[i][3] = fmaf(av, w0.w, acc[i][3]);
        acc[i][4] = fmaf(av, w1.x, acc[i][4]);
        acc[i][5] = fmaf(av, w1.y, acc[i][5]);
        acc[i][6] = fmaf(av, w1.z, acc[i][6]);
        acc[i][7] = fmaf(av, w1.w, acc[i][7]);
      }
    }
  }

  #pragma unroll
  for (int i = 0; i < 8; ++i){
    int r = r0 + rg + 16*i;
    #pragma unroll
    for (int jj = 0; jj < 2; ++jj){
      float4 o;
      o.x = acc[i][jj*4+0]; o.y = acc[i][jj*4+1];
      o.z = acc[i][jj*4+2]; o.w = acc[i][jj*4+3];
      *(float4*)&out[r*128 + jj*64 + cg*4] = o;
    }
  }
}

// ---------------- attention per (graph, head) ----------------
__global__ __launch_bounds__(256) void k_attn(
    const float* __restrict__ Qp, const float* __restrict__ K,
    const float* __restrict__ V, float* __restrict__ Oat)
{
  __shared__ __align__(16) float Pr[32*260];
  __shared__ __align__(16) float Vs[256*36];
  const int t = threadIdx.x;                    // = key index p
  const int b = blockIdx.x >> 2, h = blockIdx.x & 3;

  float kreg[32];
  {
    const float* kp = K + (b*256 + t)*128 + h*32;
    #pragma unroll
    for (int q = 0; q < 8; ++q){
      const float4 v = *(const float4*)&kp[q*4];
      kreg[4*q]   = v.x; kreg[4*q+1] = v.y;
      kreg[4*q+2] = v.z; kreg[4*q+3] = v.w;
    }
    const float* vp = V + (b*256 + t)*128 + h*32;
    #pragma unroll
    for (int q = 0; q < 8; ++q)
      *(float4*)&Vs[t*36 + q*4] = *(const float4*)&vp[q*4];
  }
  const float* qb = Qp + (b*32)*128 + h*32;
  #pragma unroll 1
  for (int s = 0; s < 32; ++s){
    float acc = 0.f;
    #pragma unroll
    for (int d = 0; d < 32; ++d)
      acc = fmaf(qb[s*128 + d], kreg[d], acc);
    Pr[s*260 + t] = acc * 0.08838834764831845f;
  }
  __syncthreads();
  {
    const int ss = t >> 3, pg = t & 7;
    float vals[32];
    float m = -1e30f;
    #pragma unroll
    for (int u = 0; u < 32; ++u){
      vals[u] = Pr[ss*260 + pg + 8*u];
      m = fmaxf(m, vals[u]);
    }
    m = fmaxf(m, __shfl_xor(m, 1));
    m = fmaxf(m, __shfl_xor(m, 2));
    m = fmaxf(m, __shfl_xor(m, 4));
    float sum = 0.f;
    #pragma unroll
    for (int u = 0; u < 32; ++u){
      vals[u] = __expf(vals[u] - m);
      sum += vals[u];
    }
    sum += __shfl_xor(sum, 1);
    sum += __shfl_xor(sum, 2);
    sum += __shfl_xor(sum, 4);
    float inv = 1.f / sum;
    #pragma unroll
    for (int u = 0; u < 32; ++u)
      Pr[ss*260 + pg + 8*u] = vals[u] * inv;
  }
  __syncthreads();
  {
    const int ss = t >> 3, dg = t & 7;
    float o0=0.f,o1=0.f,o2=0.f,o3=0.f;
    #pragma unroll 4
    for (int p = 0; p < 256; ++p){
      float a = Pr[ss*260 + p];
      const float4 v = *(const float4*)&Vs[p*36 + dg*4];
      o0 = fmaf(a, v.x, o0); o1 = fmaf(a, v.y, o1);
      o2 = fmaf(a, v.z, o2); o3 = fmaf(a, v.w, o3);
    }
    const int off = (b*32 + ss)*128 + h*32 + dg*4;
    const float4 q = *(const float4*)(Qp + off);
    float4 o; o.x = o0+q.x; o.y = o1+q.y; o.z = o2+q.z; o.w = o3+q.w;
    *(float4*)(Oat + off) = o;
  }
}

// ---------------- epilogue: LN0 -> +relu(.@Wo+bo) -> LN1 -> f32 out ----------------
__global__ __launch_bounds__(256) void k_epi(
    const float* __restrict__ Oat, const float* __restrict__ Wo,
    const float* __restrict__ bo, const float* __restrict__ g0,
    const float* __restrict__ b0, const float* __restrict__ g1,
    const float* __restrict__ b1, float* __restrict__ out)
{
  __shared__ float rb[4][132];
  const int w = threadIdx.x >> 6, lane = threadIdx.x & 63;
  const int row = blockIdx.x*4 + w;
  const float2 xv = *(const float2*)(Oat + row*128 + 2*lane);
  float x0 = xv.x, x1 = xv.y;
  float s = x0 + x1;
  s += __shfl_xor(s,1); s += __shfl_xor(s,2); s += __shfl_xor(s,4);
  s += __shfl_xor(s,8); s += __shfl_xor(s,16); s += __shfl_xor(s,32);
  float mu = s * 0.0078125f;
  float d0 = x0 - mu, d1 = x1 - mu;
  float vv = d0*d0 + d1*d1;
  vv += __shfl_xor(vv,1); vv += __shfl_xor(vv,2); vv += __shfl_xor(vv,4);
  vv += __shfl_xor(vv,8); vv += __shfl_xor(vv,16); vv += __shfl_xor(vv,32);
  float rs = rsqrtf(vv*0.0078125f + 1e-5f);
  const float2 gv = *(const float2*)&g0[2*lane];
  const float2 bv = *(const float2*)&b0[2*lane];
  float y0 = d0*rs*gv.x + bv.x;
  float y1 = d1*rs*gv.y + bv.y;
  rb[w][2*lane] = y0; rb[w][2*lane+1] = y1;
  __syncthreads();
  const float2 bov = *(const float2*)&bo[2*lane];
  float a0 = bov.x, a1 = bov.y;
  #pragma unroll 4
  for (int k = 0; k < 128; ++k){
    float yk = rb[w][k];
    const float2 wv = *(const float2*)&Wo[k*128 + 2*lane];
    a0 = fmaf(yk, wv.x, a0);
    a1 = fmaf(yk, wv.y, a1);
  }
  float z0 = y0 + fmaxf(a0, 0.f);
  float z1 = y1 + fmaxf(a1, 0.f);
  s = z0 + z1;
  s += __shfl_xor(s,1); s += __shfl_xor(s,2); s += __shfl_xor(s,4);
  s += __shfl_xor(s,8); s += __shfl_xor(s,16); s += __shfl_xor(s,32);
  mu = s * 0.0078125f;
  d0 = z0 - mu; d1 = z1 - mu;
  vv = d0*d0 + d1*d1;
  vv += __shfl_xor(vv,1); vv += __shfl_xor(vv,2); vv += __shfl_xor(vv,4);
  vv += __shfl_xor(vv,8); vv += __shfl_xor(vv,16); vv += __shfl_xor(vv,32);
  rs = rsqrtf(vv*0.0078125f + 1e-5f);
  const float2 g1v = *(const float2*)&g1[2*lane];
  const float2 b1v = *(const float2*)&b1[2*lane];
  float o0 = d0*rs*g1v.x + b1v.x;
  float o1 = d1*rs*g1v.y + b1v.y;
  float2 o; o.x = o0; o.y = o1;
  *(float2*)&out[row*128 + 2*lane] = o;
}

extern "C" void kernel_launch(void* const* d_in, const int* in_sizes, int n_in,
                              void* d_out, int out_size, void* d_ws, size_t ws_size,
                              hipStream_t stream){
  const float* Q   = (const float*)d_in[0];
  const float* x   = (const float*)d_in[1];
  const int*   ei  = (const int*)d_in[2];
  const float* Wq  = (const float*)d_in[4];
  const float* bq  = (const float*)d_in[5];
  const float* Wk  = (const float*)d_in[6];
  const float* bk  = (const float*)d_in[7];
  const float* Wv  = (const float*)d_in[8];
  const float* bv  = (const float*)d_in[9];
  const float* Wo  = (const float*)d_in[10];
  const float* bo  = (const float*)d_in[11];
  const float* g0  = (const float*)d_in[12];
  const float* b0  = (const float*)d_in[13];
  const float* g1  = (const float*)d_in[14];
  const float* b1  = (const float*)d_in[15];

  // workspace layout (time-aliased)
  char* ws = (char*)d_ws;
  float* xa   = (float*)(ws);                    // [0,16M)
  float* Kf   = (float*)(ws + 16777216);         // [16M,32M)
  float* Vf   = (float*)(ws + 33554432);         // [32M,48M)
  float* Qp   = (float*)(ws + 50331648);         // [48M,50M)
  float* Oat  = (float*)(ws + 52428800);         // [50M,52M)
  float* dinv = (float*)(ws + 54525952);         // [52M,+128K)
  int*   cnt  = (int*)(ws + 16777216);           // aliases Kf   (dead before gemm3)
  int*   start= (int*)(ws + 33554432);           // aliases Vf   (dead before gemm3)
  int*   wptr = (int*)(ws + 50331648);           // aliases Qp   (dead before gemm3)
  int*   ssrc = (int*)(ws + 52428800);           // aliases Oat  (dead before attn)

  k_zero<<<32, 256, 0, stream>>>((int4*)cnt);
  k_hist<<<NEDGE/256, 256, 0, stream>>>(ei + NEDGE, cnt);
  k_scan<<<1, 1024, 0, stream>>>(cnt, start, wptr, dinv);
  k_sort<<<NEDGE/256, 256, 0, stream>>>(ei, wptr, ssrc);
  k_gather<<<NGRAPH*2, 512, 0, stream>>>(start, ssrc, x, dinv, xa);
  k_gemm3<<<544, 256, 0, stream>>>(xa, Q, Wk, bk, Kf, Wv, bv, Vf, Wq, bq, Qp);
  k_attn<<<NGRAPH*NHEAD, 256, 0, stream>>>(Qp, Kf, Vf, Oat);
  k_epi<<<(NGRAPH*SQ)/4, 256, 0, stream>>>(Oat, Wo, bo, g0, b0, g1, b1, (float*)d_out);
}

// Round 5
// 163.270 us; speedup vs baseline: 3.5682x; 1.2688x over previous
//
#include <hip/hip_runtime.h>

typedef unsigned int uint32;
typedef unsigned short ushort;
typedef __attribute__((ext_vector_type(8))) short short8;   // 8 bf16 = 4 VGPR
typedef __attribute__((ext_vector_type(4))) float f32x4;

#define NNODES 32768
#define NGRAPH 128
#define PNODES 256
#define SQ 32
#define NEDGE 524288
#define DIM 128
#define NHEAD 4

__device__ __forceinline__ uint32 f2bf(float f){
  union{float f; uint32 i;} c; c.f=f;
  return (c.i + 0x7FFFu + ((c.i>>16)&1u)) >> 16;
}
__device__ __forceinline__ uint32 pk2(float a, float b){ return f2bf(a) | (f2bf(b)<<16); }

// ---------------- zero the histogram ----------------
__global__ void k_zero(int4* __restrict__ p){
  p[blockIdx.x*256 + threadIdx.x] = int4{0,0,0,0};   // grid exact: 32
}

// ---------------- histogram of dst ----------------
__global__ void k_hist(const int* __restrict__ dst, int* __restrict__ cnt){
  int e = blockIdx.x*256 + threadIdx.x;
  atomicAdd(&cnt[dst[e]], 1);
}

// ---------------- prefix sum + dinv ----------------
__global__ __launch_bounds__(1024) void k_scan(const int* __restrict__ cnt,
                                               int* __restrict__ start,
                                               int* __restrict__ wptr,
                                               float* __restrict__ dinv){
  __shared__ int ps[1024];
  const int t = threadIdx.x;
  const int base = t*32;
  int loc[32];
  int s = 0;
  #pragma unroll
  for (int i = 0; i < 32; ++i){
    int c = cnt[base+i];
    loc[i] = s; s += c;
    dinv[base+i] = rsqrtf((float)(c + 1));
  }
  ps[t] = s;
  __syncthreads();
  #pragma unroll 1
  for (int off = 1; off < 1024; off <<= 1){
    int v = (t >= off) ? ps[t-off] : 0;
    __syncthreads();
    ps[t] += v;
    __syncthreads();
  }
  const int pre = (t == 0) ? 0 : ps[t-1];
  #pragma unroll
  for (int i = 0; i < 32; ++i){
    int v = pre + loc[i];
    start[base+i] = v;
    wptr[base+i]  = v;
  }
  if (t == 0) start[NNODES] = NEDGE;
}

// ---------------- bucket edges by dst ----------------
__global__ void k_sort(const int* __restrict__ ei, int* __restrict__ wptr,
                       int* __restrict__ ssrc){
  int e = blockIdx.x*256 + threadIdx.x;
  int s = ei[e];
  int d = ei[NEDGE + e];
  int pos = atomicAdd(&wptr[d], 1);
  ssrc[pos] = s;
}

// ---------------- one-time weight transpose+convert: WT[n][k] = bf16(W[k][n]) ----------------
__global__ __launch_bounds__(256) void k_prep(const float* __restrict__ Wk,
    const float* __restrict__ Wv, const float* __restrict__ Wq,
    ushort* __restrict__ WTk, ushort* __restrict__ WTv, ushort* __restrict__ WTq){
  __shared__ __align__(16) float Ws2[128*132];
  const float* W = (blockIdx.x==0) ? Wk : (blockIdx.x==1) ? Wv : Wq;
  ushort* WT     = (blockIdx.x==0) ? WTk : (blockIdx.x==1) ? WTv : WTq;
  const int t = threadIdx.x;
  for (int idx = t; idx < 4096; idx += 256){
    int k = idx >> 5, c4 = idx & 31;
    *(float4*)&Ws2[k*132 + c4*4] = *(const float4*)&W[k*128 + c4*4];
  }
  __syncthreads();
  for (int idx = t; idx < 2048; idx += 256){
    int n = idx & 127, c8 = idx >> 7;       // n fastest -> conflict-free LDS reads
    uint4 p;
    p.x = pk2(Ws2[(c8*8+0)*132 + n], Ws2[(c8*8+1)*132 + n]);
    p.y = pk2(Ws2[(c8*8+2)*132 + n], Ws2[(c8*8+3)*132 + n]);
    p.z = pk2(Ws2[(c8*8+4)*132 + n], Ws2[(c8*8+5)*132 + n]);
    p.w = pk2(Ws2[(c8*8+6)*132 + n], Ws2[(c8*8+7)*132 + n]);
    *(uint4*)&WT[n*128 + c8*8] = p;
  }
}

// ---------------- gather with per-graph LDS staging -> packed bf16 xa ----------------
__global__ __launch_bounds__(512) void k_gather(const int* __restrict__ start,
    const int* __restrict__ ssrc, const float* __restrict__ x,
    const float* __restrict__ dinv, uint32* __restrict__ xab){
  __shared__ __align__(16) float xs[PNODES*DIM];   // 128 KB
  __shared__ float dvs[PNODES];
  const int g = blockIdx.x >> 1;
  const int half = blockIdx.x & 1;
  const int t = threadIdx.x;
  const int base = g*PNODES;

  {
    const float4* xg = (const float4*)&x[base*DIM];
    float4* xs4 = (float4*)xs;
    #pragma unroll
    for (int i = 0; i < 16; ++i)
      xs4[t + i*512] = xg[t + i*512];
    if (t < PNODES) dvs[t] = dinv[base + t];
  }
  __syncthreads();

  const int wave = t >> 6, lane = t & 63;
  #pragma unroll 1
  for (int ni = 0; ni < 16; ++ni){
    const int nl = __builtin_amdgcn_readfirstlane(half*128 + wave*16 + ni);
    const int n  = base + nl;
    const int s0 = start[n], s1 = start[n+1];
    const float dn = dvs[nl];
    const float2 xv = *(const float2*)&xs[nl*DIM + 2*lane];
    float a0 = dn*dn*xv.x, a1 = dn*dn*xv.y;
    int e = s0;
    for (; e + 2 <= s1; e += 2){
      int slA = ssrc[e]   - base;
      int slB = ssrc[e+1] - base;
      float cA = dn*dvs[slA], cB = dn*dvs[slB];
      const float2 vA = *(const float2*)&xs[slA*DIM + 2*lane];
      const float2 vB = *(const float2*)&xs[slB*DIM + 2*lane];
      a0 = fmaf(cA, vA.x, a0); a1 = fmaf(cA, vA.y, a1);
      a0 = fmaf(cB, vB.x, a0); a1 = fmaf(cB, vB.y, a1);
    }
    if (e < s1){
      int slA = ssrc[e] - base;
      float cA = dn*dvs[slA];
      const float2 vA = *(const float2*)&xs[slA*DIM + 2*lane];
      a0 = fmaf(cA, vA.x, a0); a1 = fmaf(cA, vA.y, a1);
    }
    xab[n*64 + lane] = pk2(a0, a1);
  }
}

// ---------------- fused MFMA GEMM: Q (blk 0-31), K (32-287), V (288-543) ----------------
// out[M,128] = bf16(in)[M,128] @ bf16(W)[128,128] + b, f32 accum/output
__global__ __launch_bounds__(256) void k_gemm3(
    const ushort* __restrict__ xab, const float* __restrict__ Qin,
    const ushort* __restrict__ WTk, const float* __restrict__ bk, float* __restrict__ Kf,
    const ushort* __restrict__ WTv, const float* __restrict__ bv, float* __restrict__ Vf,
    const ushort* __restrict__ WTq, const float* __restrict__ bq, float* __restrict__ Qp)
{
  __shared__ __align__(16) ushort As[128*136];   // [m][k] bf16, pad 136
  __shared__ __align__(16) ushort Bs[128*136];   // [n][k] bf16 (W^T), pad 136
  const int bid = blockIdx.x;
  const int t = threadIdx.x;

  const ushort* WT; const float* bias; float* out; int r0; bool qpath;
  if (bid < 32){ WT = WTq; bias = bq; out = Qp; r0 = bid*128; qpath = true; }
  else if (bid < 288){ WT = WTk; bias = bk; out = Kf; r0 = (bid-32)*128; qpath = false; }
  else { WT = WTv; bias = bv; out = Vf; r0 = (bid-288)*128; qpath = false; }

  for (int idx = t; idx < 2048; idx += 256){
    int n = idx >> 4, c8 = idx & 15;
    *(uint4*)&Bs[n*136 + c8*8] = *(const uint4*)&WT[n*128 + c8*8];
  }
  if (qpath){
    for (int idx = t; idx < 2048; idx += 256){
      int r = idx >> 4, c8 = idx & 15;
      const float4 f0 = *(const float4*)&Qin[(r0+r)*128 + c8*8];
      const float4 f1 = *(const float4*)&Qin[(r0+r)*128 + c8*8 + 4];
      uint4 p; p.x = pk2(f0.x,f0.y); p.y = pk2(f0.z,f0.w);
      p.z = pk2(f1.x,f1.y); p.w = pk2(f1.z,f1.w);
      *(uint4*)&As[r*136 + c8*8] = p;
    }
  } else {
    for (int idx = t; idx < 2048; idx += 256){
      int r = idx >> 4, c8 = idx & 15;
      *(uint4*)&As[r*136 + c8*8] = *(const uint4*)&xab[(r0+r)*128 + c8*8];
    }
  }
  __syncthreads();

  const int lane = t & 63, w = t >> 6;
  const int r16 = lane & 15, kg = lane >> 4;

  f32x4 acc[2][8];
  #pragma unroll
  for (int i = 0; i < 2; ++i)
    #pragma unroll
    for (int j = 0; j < 8; ++j)
      acc[i][j] = (f32x4){0.f, 0.f, 0.f, 0.f};

  #pragma unroll
  for (int kc = 0; kc < 4; ++kc){
    const short8 a0 = *(const short8*)&As[(w*32      + r16)*136 + kc*32 + kg*8];
    const short8 a1 = *(const short8*)&As[(w*32 + 16 + r16)*136 + kc*32 + kg*8];
    #pragma unroll
    for (int ct = 0; ct < 8; ++ct){
      const short8 bfr = *(const short8*)&Bs[(ct*16 + r16)*136 + kc*32 + kg*8];
      acc[0][ct] = __builtin_amdgcn_mfma_f32_16x16x32_bf16(a0, bfr, acc[0][ct], 0, 0, 0);
      acc[1][ct] = __builtin_amdgcn_mfma_f32_16x16x32_bf16(a1, bfr, acc[1][ct], 0, 0, 0);
    }
  }

  // D: row = (lane>>4)*4 + q, col = lane&15  (m89-verified)
  #pragma unroll
  for (int ct = 0; ct < 8; ++ct){
    const float bc = bias[ct*16 + r16];
    #pragma unroll
    for (int rt = 0; rt < 2; ++rt){
      const int row = r0 + w*32 + rt*16 + kg*4;
      #pragma unroll
      for (int q = 0; q < 4; ++q)
        out[(row+q)*128 + ct*16 + r16] = acc[rt][ct][q] + bc;
    }
  }
}

// ---------------- attention per (graph, head) ----------------
__global__ __launch_bounds__(256) void k_attn(
    const float* __restrict__ Qp, const float* __restrict__ K,
    const float* __restrict__ V, float* __restrict__ Oat)
{
  __shared__ __align__(16) float Pr[32*260];
  __shared__ __align__(16) float Vs[256*36];
  const int t = threadIdx.x;                    // = key index p
  const int b = blockIdx.x >> 2, h = blockIdx.x & 3;

  float kreg[32];
  {
    const float* kp = K + (b*256 + t)*128 + h*32;
    #pragma unroll
    for (int q = 0; q < 8; ++q){
      const float4 v = *(const float4*)&kp[q*4];
      kreg[4*q]   = v.x; kreg[4*q+1] = v.y;
      kreg[4*q+2] = v.z; kreg[4*q+3] = v.w;
    }
    const float* vp = V + (b*256 + t)*128 + h*32;
    #pragma unroll
    for (int q = 0; q < 8; ++q)
      *(float4*)&Vs[t*36 + q*4] = *(const float4*)&vp[q*4];
  }
  const float* qb = Qp + (b*32)*128 + h*32;
  #pragma unroll 1
  for (int s = 0; s < 32; ++s){
    float acc = 0.f;
    #pragma unroll
    for (int d = 0; d < 32; ++d)
      acc = fmaf(qb[s*128 + d], kreg[d], acc);
    Pr[s*260 + t] = acc * 0.08838834764831845f;
  }
  __syncthreads();
  {
    const int ss = t >> 3, pg = t & 7;
    float vals[32];
    float m = -1e30f;
    #pragma unroll
    for (int u = 0; u < 32; ++u){
      vals[u] = Pr[ss*260 + pg + 8*u];
      m = fmaxf(m, vals[u]);
    }
    m = fmaxf(m, __shfl_xor(m, 1));
    m = fmaxf(m, __shfl_xor(m, 2));
    m = fmaxf(m, __shfl_xor(m, 4));
    float sum = 0.f;
    #pragma unroll
    for (int u = 0; u < 32; ++u){
      vals[u] = __expf(vals[u] - m);
      sum += vals[u];
    }
    sum += __shfl_xor(sum, 1);
    sum += __shfl_xor(sum, 2);
    sum += __shfl_xor(sum, 4);
    float inv = 1.f / sum;
    #pragma unroll
    for (int u = 0; u < 32; ++u)
      Pr[ss*260 + pg + 8*u] = vals[u] * inv;
  }
  __syncthreads();
  {
    const int ss = t >> 3, dg = t & 7;
    float o0=0.f,o1=0.f,o2=0.f,o3=0.f;
    #pragma unroll 4
    for (int p = 0; p < 256; ++p){
      float a = Pr[ss*260 + p];
      const float4 v = *(const float4*)&Vs[p*36 + dg*4];
      o0 = fmaf(a, v.x, o0); o1 = fmaf(a, v.y, o1);
      o2 = fmaf(a, v.z, o2); o3 = fmaf(a, v.w, o3);
    }
    const int off = (b*32 + ss)*128 + h*32 + dg*4;
    const float4 q = *(const float4*)(Qp + off);
    float4 o; o.x = o0+q.x; o.y = o1+q.y; o.z = o2+q.z; o.w = o3+q.w;
    *(float4*)(Oat + off) = o;
  }
}

// ---------------- epilogue: LN0 -> +relu(.@Wo+bo) -> LN1 -> f32 out ----------------
__global__ __launch_bounds__(256) void k_epi(
    const float* __restrict__ Oat, const float* __restrict__ Wo,
    const float* __restrict__ bo, const float* __restrict__ g0,
    const float* __restrict__ b0, const float* __restrict__ g1,
    const float* __restrict__ b1, float* __restrict__ out)
{
  __shared__ float rb[4][132];
  const int w = threadIdx.x >> 6, lane = threadIdx.x & 63;
  const int row = blockIdx.x*4 + w;
  const float2 xv = *(const float2*)(Oat + row*128 + 2*lane);
  float x0 = xv.x, x1 = xv.y;
  float s = x0 + x1;
  s += __shfl_xor(s,1); s += __shfl_xor(s,2); s += __shfl_xor(s,4);
  s += __shfl_xor(s,8); s += __shfl_xor(s,16); s += __shfl_xor(s,32);
  float mu = s * 0.0078125f;
  float d0 = x0 - mu, d1 = x1 - mu;
  float vv = d0*d0 + d1*d1;
  vv += __shfl_xor(vv,1); vv += __shfl_xor(vv,2); vv += __shfl_xor(vv,4);
  vv += __shfl_xor(vv,8); vv += __shfl_xor(vv,16); vv += __shfl_xor(vv,32);
  float rs = rsqrtf(vv*0.0078125f + 1e-5f);
  const float2 gv = *(const float2*)&g0[2*lane];
  const float2 bv = *(const float2*)&b0[2*lane];
  float y0 = d0*rs*gv.x + bv.x;
  float y1 = d1*rs*gv.y + bv.y;
  rb[w][2*lane] = y0; rb[w][2*lane+1] = y1;
  __syncthreads();
  const float2 bov = *(const float2*)&bo[2*lane];
  float a0 = bov.x, a1 = bov.y;
  #pragma unroll 4
  for (int k = 0; k < 128; ++k){
    float yk = rb[w][k];
    const float2 wv = *(const float2*)&Wo[k*128 + 2*lane];
    a0 = fmaf(yk, wv.x, a0);
    a1 = fmaf(yk, wv.y, a1);
  }
  float z0 = y0 + fmaxf(a0, 0.f);
  float z1 = y1 + fmaxf(a1, 0.f);
  s = z0 + z1;
  s += __shfl_xor(s,1); s += __shfl_xor(s,2); s += __shfl_xor(s,4);
  s += __shfl_xor(s,8); s += __shfl_xor(s,16); s += __shfl_xor(s,32);
  mu = s * 0.0078125f;
  d0 = z0 - mu; d1 = z1 - mu;
  vv = d0*d0 + d1*d1;
  vv += __shfl_xor(vv,1); vv += __shfl_xor(vv,2); vv += __shfl_xor(vv,4);
  vv += __shfl_xor(vv,8); vv += __shfl_xor(vv,16); vv += __shfl_xor(vv,32);
  rs = rsqrtf(vv*0.0078125f + 1e-5f);
  const float2 g1v = *(const float2*)&g1[2*lane];
  const float2 b1v = *(const float2*)&b1[2*lane];
  float o0 = d0*rs*g1v.x + b1v.x;
  float o1 = d1*rs*g1v.y + b1v.y;
  float2 o; o.x = o0; o.y = o1;
  *(float2*)&out[row*128 + 2*lane] = o;
}

extern "C" void kernel_launch(void* const* d_in, const int* in_sizes, int n_in,
                              void* d_out, int out_size, void* d_ws, size_t ws_size,
                              hipStream_t stream){
  const float* Q   = (const float*)d_in[0];
  const float* x   = (const float*)d_in[1];
  const int*   ei  = (const int*)d_in[2];
  const float* Wq  = (const float*)d_in[4];
  const float* bq  = (const float*)d_in[5];
  const float* Wk  = (const float*)d_in[6];
  const float* bk  = (const float*)d_in[7];
  const float* Wv  = (const float*)d_in[8];
  const float* bv  = (const float*)d_in[9];
  const float* Wo  = (const float*)d_in[10];
  const float* bo  = (const float*)d_in[11];
  const float* g0  = (const float*)d_in[12];
  const float* b0  = (const float*)d_in[13];
  const float* g1  = (const float*)d_in[14];
  const float* b1  = (const float*)d_in[15];

  // workspace layout (time-aliased)
  char* ws = (char*)d_ws;
  uint32* xab = (uint32*)(ws);                   // [0,8M)  bf16-packed xa
  ushort* WTk = (ushort*)(ws + 8388608);         // 64 KB slots
  ushort* WTv = (ushort*)(ws + 8454144);
  ushort* WTq = (ushort*)(ws + 8519680);
  float* Kf   = (float*)(ws + 16777216);         // [16M,32M)
  float* Vf   = (float*)(ws + 33554432);         // [32M,48M)
  float* Qp   = (float*)(ws + 50331648);         // [48M,50M)
  float* Oat  = (float*)(ws + 52428800);         // [50M,52M)
  float* dinv = (float*)(ws + 54525952);         // [52M,+128K)
  int*   cnt  = (int*)(ws + 16777216);           // aliases Kf   (dead before gemm3)
  int*   start= (int*)(ws + 33554432);           // aliases Vf   (dead after gather)
  int*   wptr = (int*)(ws + 50331648);           // aliases Qp   (dead after sort)
  int*   ssrc = (int*)(ws + 52428800);           // aliases Oat  (dead after gather)

  k_zero<<<32, 256, 0, stream>>>((int4*)cnt);
  k_hist<<<NEDGE/256, 256, 0, stream>>>(ei + NEDGE, cnt);
  k_scan<<<1, 1024, 0, stream>>>(cnt, start, wptr, dinv);
  k_sort<<<NEDGE/256, 256, 0, stream>>>(ei, wptr, ssrc);
  k_prep<<<3, 256, 0, stream>>>(Wk, Wv, Wq, WTk, WTv, WTq);
  k_gather<<<NGRAPH*2, 512, 0, stream>>>(start, ssrc, x, dinv, xab);
  k_gemm3<<<544, 256, 0, stream>>>((const ushort*)xab, Q, WTk, bk, Kf, WTv, bv, Vf, WTq, bq, Qp);
  k_attn<<<NGRAPH*NHEAD, 256, 0, stream>>>(Qp, Kf, Vf, Oat);
  k_epi<<<(NGRAPH*SQ)/4, 256, 0, stream>>>(Oat, Wo, bo, g0, b0, g1, b1, (float*)d_out);
}